// Round 4
// baseline (99.382 us; speedup 1.0000x reference)
//
#include <hip/hip_runtime.h>
#include <hip/hip_bf16.h>
#include <math.h>

#define B_   8
#define C_   32
#define H_   256
#define W_   256
#define NPIX (B_*C_*H_*W_)   // offset of logdet in d_out

typedef __attribute__((ext_vector_type(8))) short short8;   // bf16x8 MFMA A/B frag
typedef __attribute__((ext_vector_type(4))) float f32x4;    // fp32x4 MFMA C/D frag

static __device__ __forceinline__ short f2bf(float f) {
    union { __hip_bfloat16 h; short s; } u; u.h = __float2bfloat16(f); return u.s;
}
static __device__ __forceinline__ int packbf(float a, float b) {
    return (int)(unsigned short)f2bf(a) | ((int)(unsigned short)f2bf(b) << 16);
}

// ---------------------------------------------------------------------------
// Prep: weight-norm -> bf16.
//   w1b[o*192 + tap*32 + c]                       (tap = kh*3+kw)
//   w2b[j*64 + slot]: hidden-dim permutation so conv2 B-frags are lane-local:
//     channel c (mt=c>>4, q=(c>>2)&3, reg=c&3) -> slot (mt>>1)*32+q*8+(mt&1)*4+reg
// ---------------------------------------------------------------------------
__global__ __launch_bounds__(64) void prep_kernel(
    const float* __restrict__ v1, const float* __restrict__ g1,
    const float* __restrict__ v2, const float* __restrict__ g2,
    short* __restrict__ w1b, short* __restrict__ w2b,
    float* __restrict__ logdet)
{
    const int t   = threadIdx.x;   // 0..63
    const int bid = blockIdx.x;    // 0..127
    if (bid < 64) {
        const int o = bid;
        float a0 = v1[o*192 + t];
        float a1 = v1[o*192 + t + 64];
        float a2 = v1[o*192 + t + 128];
        float s  = a0*a0 + a1*a1 + a2*a2;
        #pragma unroll
        for (int m = 32; m >= 1; m >>= 1) s += __shfl_xor(s, m, 64);
        const float inv = g1[o] / sqrtf(s);
        const int e0 = t, e1 = t + 64, e2 = t + 128;   // src idx = c*6 + tap
        w1b[o*192 + (e0%6)*32 + e0/6] = f2bf(a0*inv);
        w1b[o*192 + (e1%6)*32 + e1/6] = f2bf(a1*inv);
        w1b[o*192 + (e2%6)*32 + e2/6] = f2bf(a2*inv);
        if (bid == 0 && t < B_) logdet[t] = 0.f;       // zero logdet every launch
    } else {
        const int j = bid - 64;
        float a = v2[j*64 + t];
        float s = a*a;
        #pragma unroll
        for (int m = 32; m >= 1; m >>= 1) s += __shfl_xor(s, m, 64);
        const float inv = g2[j] / sqrtf(s);
        const int mt = t >> 4, r = t & 15;
        const int slot = (mt >> 1)*32 + ((r >> 2) << 3) + ((mt & 1) << 2) + (r & 3);
        w2b[j*64 + slot] = f2bf(a*inv);
    }
}

// ---------------------------------------------------------------------------
// Fused MFMA kernel: one block per (b, row-pair h0,h0+1). 4 waves, 64 px each.
// Grid = 1024 blocks = 4/CU x 256 CU -> fully resident, single generation.
// LDS: 2-slot ring of staged bf16 x rows (slot = row & 1), 16 KB each:
//   dword(slot,w,cp) = slot*4096 + w*16 + ((cp>>2) ^ ((w>>2)&3))*4 + (cp&3)
// conv1: D1[o][px] (A = weights, B = x-patch) -> lane holds o=4q+reg, px=lrow
// conv2: lane-local B-frags (hidden dim pre-permuted), everything else in reg.
// ---------------------------------------------------------------------------
__global__ __launch_bounds__(256, 4) void flow_kernel(
    const float* __restrict__ x,
    const short* __restrict__ w1b, const short* __restrict__ w2b,
    const float* __restrict__ b1,  const float* __restrict__ b2,
    float* __restrict__ out, float* __restrict__ logdet)
{
    __shared__ int ldsI[8192];     // 32 KiB: two 4096-dword slots
    __shared__ float red4[4];

    const int bi0 = blockIdx.x;            // 0..1023
    const int b   = bi0 & 7;               // image = XCD (round-robin dispatch)
    const int h0  = (bi0 >> 3) << 1;       // even output row

    const int tid  = threadIdx.x;
    const int l    = tid & 63;
    const int wv   = tid >> 6;
    const int lrow = l & 15;
    const int q    = l >> 4;

    const int w4 = (tid & 63) << 2;        // staging: pixel quad base
    const int cg = tid >> 6;               // staging: channel group (8 ch)
    const int c8 = cg << 3;

    const float* xb = x + (size_t)b * (C_*H_*W_);
    float* ob       = out + (size_t)b * (C_*H_*W_);

    // ---- staging helpers --------------------------------------------------
    auto stage_write = [&](int slotbase, const f32x4* qv) {
        #pragma unroll
        for (int p = 0; p < 4; ++p) {
            const int w  = w4 + p;
            const int sw = (w >> 2) & 3;
            int4 d;
            d.x = packbf(qv[0][p], qv[1][p]);
            d.y = packbf(qv[2][p], qv[3][p]);
            d.z = packbf(qv[4][p], qv[5][p]);
            d.w = packbf(qv[6][p], qv[7][p]);
            *(int4*)&ldsI[slotbase + w*16 + ((cg ^ sw) << 2)] = d;
        }
    };
    auto stage_row = [&](int hr, int slotbase) {
        if (hr >= 0) {
            f32x4 qv[8];
            #pragma unroll
            for (int j = 0; j < 8; ++j)
                qv[j] = *(const f32x4*)(xb + (size_t)(c8 + j)*(H_*W_) + (size_t)hr*W_ + w4);
            stage_write(slotbase, qv);
        } else {
            #pragma unroll
            for (int p = 0; p < 4; ++p) {
                const int w  = w4 + p;
                const int sw = (w >> 2) & 3;
                *(int4*)&ldsI[slotbase + w*16 + ((cg ^ sw) << 2)] = (int4){0,0,0,0};
            }
        }
    };

    // ---- one output row: conv1 -> ELU -> conv2 -> affine/logdet -----------
    auto compute_row = [&](int h) -> float {
        const int sb0 = ( h      & 1) << 14;   // byte base of row h-2
        const int sb1 = ((h + 1) & 1) << 14;   // byte base of row h-1

        f32x4 acc1[4][4];
        #pragma unroll
        for (int mt = 0; mt < 4; ++mt) {
            const f32x4 bv = *(const f32x4*)(b1 + mt*16 + 4*q);
            #pragma unroll
            for (int nt = 0; nt < 4; ++nt) acc1[mt][nt] = bv;
        }

        const short8 zero8 = {0,0,0,0,0,0,0,0};
        #pragma unroll
        for (int tap = 0; tap < 6; ++tap) {
            const int rb = (tap < 3) ? sb0 : sb1;
            const int dw = (tap % 3) - 1;
            short8 wf[4];
            #pragma unroll
            for (int mt = 0; mt < 4; ++mt)
                wf[mt] = *(const short8*)(w1b + (mt*16 + lrow)*192 + tap*32 + q*8);
            #pragma unroll
            for (int nt = 0; nt < 4; ++nt) {
                const int pxo = wv*64 + nt*16 + lrow;
                const int px  = pxo + dw;
                const int pxc = px < 0 ? 0 : (px > 255 ? 255 : px);
                const int byteoff = rb + pxc*64 + ((q ^ ((pxc >> 2) & 3)) << 4);
                short8 xf = *(const short8*)((const char*)ldsI + byteoff);
                if (px != pxc) xf = zero8;
                #pragma unroll
                for (int mt = 0; mt < 4; ++mt)
                    acc1[mt][nt] = __builtin_amdgcn_mfma_f32_16x16x32_bf16(
                                       wf[mt], xf, acc1[mt][nt], 0, 0, 0);
            }
        }

        // ELU in-register
        #pragma unroll
        for (int mt = 0; mt < 4; ++mt)
            #pragma unroll
            for (int nt = 0; nt < 4; ++nt)
                #pragma unroll
                for (int rg = 0; rg < 4; ++rg) {
                    const float v = acc1[mt][nt][rg];
                    acc1[mt][nt][rg] = v > 0.f ? v : (__expf(v) - 1.f);
                }

        // conv2: lane-local B-frags (hidden dim pre-permuted in w2b)
        short8 a2f[2][4];
        #pragma unroll
        for (int kt = 0; kt < 2; ++kt)
            #pragma unroll
            for (int mt2 = 0; mt2 < 4; ++mt2)
                a2f[kt][mt2] = *(const short8*)(w2b + (mt2*16 + lrow)*64 + kt*32 + q*8);

        f32x4 acc2[4][4];
        #pragma unroll
        for (int nt = 0; nt < 4; ++nt) {
            short8 bf0, bf1;
            #pragma unroll
            for (int rg = 0; rg < 4; ++rg) {
                bf0[rg]     = f2bf(acc1[0][nt][rg]);
                bf0[rg + 4] = f2bf(acc1[1][nt][rg]);
                bf1[rg]     = f2bf(acc1[2][nt][rg]);
                bf1[rg + 4] = f2bf(acc1[3][nt][rg]);
            }
            #pragma unroll
            for (int mt2 = 0; mt2 < 4; ++mt2) {
                f32x4 t0 = __builtin_amdgcn_mfma_f32_16x16x32_bf16(
                               a2f[0][mt2], bf0, (f32x4){0.f,0.f,0.f,0.f}, 0, 0, 0);
                acc2[mt2][nt] = __builtin_amdgcn_mfma_f32_16x16x32_bf16(
                               a2f[1][mt2], bf1, t0, 0, 0, 0);
            }
        }

        // epilogue: sigmoid/affine/logdet, all lane-local
        f32x4 b2m[2], b2s[2];
        #pragma unroll
        for (int mt2 = 0; mt2 < 2; ++mt2) {
            b2m[mt2] = *(const f32x4*)(b2 + mt2*16 + 4*q);
            b2s[mt2] = *(const f32x4*)(b2 + 32 + mt2*16 + 4*q);
        }

        float ldsum = 0.f;
        #pragma unroll
        for (int nt = 0; nt < 4; ++nt) {
            const int px = wv*64 + nt*16 + lrow;
            const int colbase = h*W_ + px;
            #pragma unroll
            for (int mt2 = 0; mt2 < 2; ++mt2)
                #pragma unroll
                for (int rg = 0; rg < 4; ++rg) {
                    const int j = mt2*16 + 4*q + rg;
                    const float mu = acc2[mt2][nt][rg]     + b2m[mt2][rg];
                    const float z  = acc2[mt2 + 2][nt][rg] + b2s[mt2][rg] + 2.f;
                    const float sc = 1.f / (1.f + __expf(-z));
                    ldsum += __logf(sc);
                    const size_t idx = (size_t)j * (H_*W_) + colbase;
                    ob[idx] = xb[idx] * sc + mu;
                }
        }
        return ldsum;
    };

    // ---- schedule: stage(h0-2), stage(h0-1) | compute h0 (+early loads) ----
    stage_row(h0 - 2, 0);
    stage_row(h0 - 1, 4096);
    __syncthreads();

    // early-issue first half of row h0's staging loads (hide under compute)
    f32x4 qv[8];
    #pragma unroll
    for (int j = 0; j < 4; ++j)
        qv[j] = *(const f32x4*)(xb + (size_t)(c8 + j)*(H_*W_) + (size_t)h0*W_ + w4);

    float ldsum = compute_row(h0);
    __syncthreads();                       // slot-0 reads complete

    #pragma unroll
    for (int j = 4; j < 8; ++j)
        qv[j] = *(const f32x4*)(xb + (size_t)(c8 + j)*(H_*W_) + (size_t)h0*W_ + w4);
    stage_write(0, qv);                    // row h0 -> slot 0
    __syncthreads();

    ldsum += compute_row(h0 + 1);

    // ---- logdet reduction (both rows) -------------------------------------
    #pragma unroll
    for (int m = 32; m >= 1; m >>= 1) ldsum += __shfl_xor(ldsum, m, 64);
    if (l == 0) red4[wv] = ldsum;
    __syncthreads();
    if (tid == 0) atomicAdd(&logdet[b], red4[0] + red4[1] + red4[2] + red4[3]);
}

// ---------------------------------------------------------------------------
extern "C" void kernel_launch(void* const* d_in, const int* in_sizes, int n_in,
                              void* d_out, int out_size, void* d_ws, size_t ws_size,
                              hipStream_t stream)
{
    const float* x  = (const float*)d_in[0];
    const float* v1 = (const float*)d_in[1];
    const float* g1 = (const float*)d_in[2];
    const float* b1 = (const float*)d_in[3];
    const float* v2 = (const float*)d_in[4];
    const float* g2 = (const float*)d_in[5];
    const float* b2 = (const float*)d_in[6];

    float* out    = (float*)d_out;
    float* logdet = out + NPIX;

    short* w1b = (short*)d_ws;          // 12288 bf16
    short* w2b = w1b + 12288;           //  4096 bf16

    prep_kernel<<<128, 64, 0, stream>>>(v1, g1, v2, g2, w1b, w2b, logdet);
    flow_kernel<<<B_ * H_ / 2, 256, 0, stream>>>(x, w1b, w2b, b1, b2, out, logdet);
}